// Round 4
// baseline (1617.912 us; speedup 1.0000x reference)
//
#include <hip/hip_runtime.h>
#include <math.h>

#define NB   4
#define IH   128
#define IW   128
#define NTOK 16384        // IH*IW
#define CC   96
#define HID  192
#define QKD  48
#define EPSF 1e-5f
#define INV_N (1.0f/16384.0f)

__device__ __forceinline__ float wave_sum64(float v){
    #pragma unroll
    for (int off = 32; off > 0; off >>= 1) v += __shfl_xor(v, off, 64);
    return v;
}
__device__ __forceinline__ float siluf(float x){ return x / (1.0f + expf(-x)); }
__device__ __forceinline__ float geluf(float x){ return 0.5f*x*(1.0f + erff(x*0.7071067811865475f)); }

// ---------------- 1. LayerNorm over C=96, wave per row ----------------
__global__ __launch_bounds__(256) void k_ln(const float* __restrict__ x,
                                            const float* __restrict__ w,
                                            const float* __restrict__ bb,
                                            float* __restrict__ nx){
    int row = blockIdx.x*4 + (threadIdx.x >> 6);
    int l = threadIdx.x & 63;
    const float* xr = x + (size_t)row*CC;
    float a = xr[l];
    float b = (l < 32) ? xr[64+l] : 0.0f;
    float s = wave_sum64(a + b);
    float m = s * (1.0f/96.0f);
    float d1 = a - m;
    float d2 = b - m;
    float sq = d1*d1 + ((l < 32) ? d2*d2 : 0.0f);
    float var = wave_sum64(sq) * (1.0f/96.0f);
    float rstd = rsqrtf(var + EPSF);
    float* o = nx + (size_t)row*CC;
    o[l] = d1*rstd*w[l] + bb[l];
    if (l < 32) o[64+l] = d2*rstd*w[64+l] + bb[64+l];
}

// ---------------- 2. h = silu(nx @ Wh + bh); split v/gate ----------------
__global__ __launch_bounds__(256) void k_hgemm(const float* __restrict__ nx,
                                               const float* __restrict__ Wh,
                                               const float* __restrict__ bh,
                                               float* __restrict__ vbuf,
                                               float* __restrict__ gate){
    __shared__ float xs[32*96];
    __shared__ float wt[192*36];   // wt[col][k] padded stride 36
    int tid = threadIdx.x;
    int row0 = blockIdx.x * 32;
    for (int i = tid; i < 32*96; i += 256)
        xs[i] = nx[(size_t)(row0 + i/96)*CC + (i%96)];
    int tc = tid & 31, tr = tid >> 5;
    float acc[4][6];
    #pragma unroll
    for (int i = 0; i < 4; i++)
        #pragma unroll
        for (int j = 0; j < 6; j++) acc[i][j] = 0.0f;

    for (int k0 = 0; k0 < 96; k0 += 32){
        __syncthreads();
        for (int idx = tid; idx < 32*192; idx += 256){
            int kk = idx / 192, col = idx % 192;
            wt[col*36 + kk] = Wh[(size_t)(k0+kk)*HID + col];
        }
        __syncthreads();
        #pragma unroll
        for (int k4 = 0; k4 < 8; k4++){
            float4 xa[4], wb[6];
            #pragma unroll
            for (int i = 0; i < 4; i++)
                xa[i] = *(const float4*)&xs[(tr*4+i)*96 + k0 + k4*4];
            #pragma unroll
            for (int j = 0; j < 6; j++)
                wb[j] = *(const float4*)&wt[(tc + j*32)*36 + k4*4];
            #pragma unroll
            for (int i = 0; i < 4; i++)
                #pragma unroll
                for (int j = 0; j < 6; j++){
                    acc[i][j] += xa[i].x*wb[j].x + xa[i].y*wb[j].y
                               + xa[i].z*wb[j].z + xa[i].w*wb[j].w;
                }
        }
    }
    #pragma unroll
    for (int i = 0; i < 4; i++){
        size_t row = row0 + tr*4 + i;
        #pragma unroll
        for (int j = 0; j < 6; j++){
            int col = tc + j*32;
            float hv = siluf(acc[i][j] + bh[col]);
            if (col < 96) vbuf[row*CC + col] = hv;
            else          gate[row*CC + col - 96] = hv;
        }
    }
}

// ---------------- 3. conv (patch GEMM, K-split) ----------------
__global__ __launch_bounds__(256) void k_conv(const float* __restrict__ nx,
                                              const float* __restrict__ wconv,
                                              float* __restrict__ part,
                                              int posLog, int pdimLog, int pszLog, int kTotal){
    __shared__ float pt[64*96];
    __shared__ float wt[96*100];
    int posPerImg = 1 << posLog;
    int pdim = 1 << pdimLog;
    int psz  = 1 << pszLog;
    int ksLog = 2*pszLog;
    int rowblocks = (NB << posLog) >> 6;
    int rb = blockIdx.x % rowblocks;
    int split = blockIdx.x / rowblocks;
    int tid = threadIdx.x;
    int to = tid & 15, ty = tid >> 4;
    float acc[4][6];
    #pragma unroll
    for (int i = 0; i < 4; i++)
        #pragma unroll
        for (int j = 0; j < 6; j++) acc[i][j] = 0.0f;

    for (int half = 0; half < 2; half++){
        int kb = split*192 + half*96;
        __syncthreads();
        for (int idx = tid; idx < 96*96; idx += 256){
            int o = idx / 96, kk = idx % 96;
            wt[o*100 + kk] = wconv[(size_t)o*kTotal + kb + kk];
        }
        for (int idx = tid; idx < 64*96; idx += 256){
            int r = idx / 96, kk = idx % 96;
            int R = rb*64 + r;
            int b = R >> posLog, p = R & (posPerImg-1);
            int k = kb + kk;
            int c = k >> ksLog, s = k & ((psz*psz)-1);
            int pi = p >> pdimLog, pj = p & (pdim-1);
            int px = (pi << pszLog) + (s >> pszLog);
            int py = (pj << pszLog) + (s & (psz-1));
            pt[r*96 + kk] = nx[((size_t)b*NTOK + px*IW + py)*CC + c];
        }
        __syncthreads();
        #pragma unroll 4
        for (int k4 = 0; k4 < 24; k4++){
            float4 xa[4], wb[6];
            #pragma unroll
            for (int i = 0; i < 4; i++)
                xa[i] = *(const float4*)&pt[(ty*4+i)*96 + k4*4];
            #pragma unroll
            for (int j = 0; j < 6; j++)
                wb[j] = *(const float4*)&wt[(to + j*16)*100 + k4*4];
            #pragma unroll
            for (int i = 0; i < 4; i++)
                #pragma unroll
                for (int j = 0; j < 6; j++){
                    acc[i][j] += xa[i].x*wb[j].x + xa[i].y*wb[j].y
                               + xa[i].z*wb[j].z + xa[i].w*wb[j].w;
                }
        }
    }
    int rowsTotal = NB << posLog;
    #pragma unroll
    for (int i = 0; i < 4; i++){
        int R = rb*64 + ty*4 + i;
        #pragma unroll
        for (int j = 0; j < 6; j++){
            int o = to + j*16;
            part[((size_t)split*rowsTotal + R)*96 + o] = acc[i][j];
        }
    }
}

// ---------------- 4. reduce K-splits + bias + LN + gelu + Z/q/k ----------------
__global__ __launch_bounds__(64) void k_reduce(const float* __restrict__ part,
                                               int nsplit, int rows,
                                               const float* __restrict__ cbias,
                                               const float* __restrict__ lw,
                                               const float* __restrict__ lb,
                                               const float* __restrict__ wqk,
                                               const float* __restrict__ bqk,
                                               const float* __restrict__ g,
                                               const float* __restrict__ be,
                                               float* __restrict__ qout,
                                               float* __restrict__ kout){
    __shared__ float xsh[96];
    int row = blockIdx.x;
    int l = threadIdx.x;
    float y1 = 0.0f, y2 = 0.0f;
    for (int s = 0; s < nsplit; s++){
        const float* pr = part + ((size_t)s*rows + row)*96;
        y1 += pr[l];
        if (l < 32) y2 += pr[64+l];
    }
    y1 += cbias[l];
    if (l < 32) y2 += cbias[64+l];
    float s = wave_sum64(y1 + ((l < 32) ? y2 : 0.0f));
    float m = s * (1.0f/96.0f);
    float d1 = y1 - m, d2 = y2 - m;
    float var = wave_sum64(d1*d1 + ((l < 32) ? d2*d2 : 0.0f)) * (1.0f/96.0f);
    float rstd = rsqrtf(var + EPSF);
    xsh[l] = geluf(d1*rstd*lw[l] + lb[l]);
    if (l < 32) xsh[64+l] = geluf(d2*rstd*lw[64+l] + lb[64+l]);
    __syncthreads();
    if (l < 48){
        float z = bqk[l];
        #pragma unroll 4
        for (int c = 0; c < 96; c++) z += xsh[c]*wqk[c*48 + l];
        z = siluf(z);
        qout[(size_t)row*48 + l] = z*g[l]    + be[l];
        kout[(size_t)row*48 + l] = z*g[48+l] + be[48+l];
    }
}

// ---------------- 5. attention: fused dual-GEMM, one row per thread, no LDS ----------------
// Per m: p = relu(v[row]·q[m]/N)^2 then acc += p*k[m]. q[m],k[m] are wave-uniform
// -> s_load into SGPRs (scalar pipe broadcast). P never materialized.
__global__ __launch_bounds__(256, 2) void k_attn(const float* __restrict__ vbuf,
                                                 const float* __restrict__ q1,
                                                 const float* __restrict__ k1,
                                                 const float* __restrict__ q2,
                                                 const float* __restrict__ k2,
                                                 float* __restrict__ V1,
                                                 float* __restrict__ V2){
    int bx   = blockIdx.x;
    int kind = bx >> 8;                 // 0: branch1 (M=256), 1: branch2 (M=1024)
    int blk  = bx & 255;
    int b    = blk >> 6;                // batch, uniform (64 blocks per batch)
    int row  = blk*256 + threadIdx.x;   // global row

    const float4* q4 = (const float4*)(kind ? q2 + (size_t)b*1024*48 : q1 + (size_t)b*256*48);
    const float4* k4 = (const float4*)(kind ? k2 + (size_t)b*1024*48 : k1 + (size_t)b*256*48);
    int M     = kind ? 1024 : 256;
    int voff4 = kind ? 12 : 0;
    float* vout = kind ? V2 : V1;

    float4 vv[12], acc[12];
    const float4* vr = (const float4*)(vbuf + (size_t)row*CC) + voff4;
    #pragma unroll
    for (int i = 0; i < 12; i++){ vv[i] = vr[i]; acc[i] = make_float4(0.f,0.f,0.f,0.f); }

    for (int m = 0; m < M; ++m){
        int base = __builtin_amdgcn_readfirstlane(m*12);
        float4 sq[12];
        #pragma unroll
        for (int i = 0; i < 12; i++) sq[i] = q4[base + i];
        float4 sk[12];
        #pragma unroll
        for (int i = 0; i < 12; i++) sk[i] = k4[base + i];

        float a0=0.f, a1=0.f, a2=0.f, a3=0.f;
        #pragma unroll
        for (int i = 0; i < 12; i++){
            a0 += vv[i].x*sq[i].x; a1 += vv[i].y*sq[i].y;
            a2 += vv[i].z*sq[i].z; a3 += vv[i].w*sq[i].w;
        }
        float p = ((a0+a1)+(a2+a3))*INV_N;
        p = fmaxf(p, 0.f);
        p = p*p;
        #pragma unroll
        for (int i = 0; i < 12; i++){
            acc[i].x += p*sk[i].x; acc[i].y += p*sk[i].y;
            acc[i].z += p*sk[i].z; acc[i].w += p*sk[i].w;
        }
    }
    float4* o = (float4*)(vout + (size_t)row*48);
    #pragma unroll
    for (int i = 0; i < 12; i++) o[i] = acc[i];
}

// ---------------- 6. final: xc, gate, proj, residual ----------------
__global__ __launch_bounds__(256) void k_final(const float* __restrict__ V1,
                                               const float* __restrict__ V2,
                                               const float* __restrict__ gate,
                                               const float* __restrict__ projw,
                                               const float* __restrict__ projb,
                                               float* __restrict__ out){
    __shared__ float pj[96*96];
    __shared__ float vsh[4][96];
    int tid = threadIdx.x;
    for (int i = tid; i < 96*96; i += 256) pj[i] = projw[i];
    int w = tid >> 6, l = tid & 63;
    size_t row = (size_t)blockIdx.x*4 + w;

    float xc1 = (l < 48) ? V1[row*48 + l] : V2[row*48 + (l-48)];
    float xc2 = 0.0f;
    if (l < 32) xc2 = V2[row*48 + 16 + l];
    float ga = gate[row*CC + l];
    float gb = (l < 32) ? gate[row*CC + 64 + l] : 0.0f;
    vsh[w][l] = xc1*ga;
    if (l < 32) vsh[w][64+l] = xc2*gb;
    __syncthreads();

    float a0 = projb[l];
    float a1 = (l < 32) ? projb[64+l] : 0.0f;
    #pragma unroll 4
    for (int c = 0; c < 96; c++){
        float vv = vsh[w][c];
        a0 += vv*pj[c*96 + l];
        if (l < 32) a1 += vv*pj[c*96 + 64 + l];
    }
    out[row*CC + l] = a0 + xc1;
    if (l < 32) out[row*CC + 64 + l] = a1 + xc2;
}

extern "C" void kernel_launch(void* const* d_in, const int* in_sizes, int n_in,
                              void* d_out, int out_size, void* d_ws, size_t ws_size,
                              hipStream_t stream){
    const float* x      = (const float*)d_in[0];
    const float* norm_w = (const float*)d_in[3];
    const float* norm_b = (const float*)d_in[4];
    const float* Wh     = (const float*)d_in[5];
    const float* bh     = (const float*)d_in[6];
    const float* Wqk    = (const float*)d_in[7];
    const float* bqk    = (const float*)d_in[8];
    const float* g1     = (const float*)d_in[9];
    const float* be1    = (const float*)d_in[10];
    const float* g2     = (const float*)d_in[11];
    const float* be2    = (const float*)d_in[12];
    const float* sr1_w  = (const float*)d_in[13];
    const float* sr1_b  = (const float*)d_in[14];
    const float* sr2_w  = (const float*)d_in[15];
    const float* sr2_b  = (const float*)d_in[16];
    const float* n1_w   = (const float*)d_in[17];
    const float* n1_b   = (const float*)d_in[18];
    const float* n2_w   = (const float*)d_in[19];
    const float* n2_b   = (const float*)d_in[20];
    const float* proj_w = (const float*)d_in[21];
    const float* proj_b = (const float*)d_in[22];
    float* out = (float*)d_out;

    float* ws = (float*)d_ws;
    size_t off = 0;
    float* nx   = ws + off; off += (size_t)NB*NTOK*CC;
    float* vbuf = ws + off; off += (size_t)NB*NTOK*CC;
    float* gate = ws + off; off += (size_t)NB*NTOK*CC;
    float* q1   = ws + off; off += (size_t)NB*256*48;
    float* k1   = ws + off; off += (size_t)NB*256*48;
    float* q2   = ws + off; off += (size_t)NB*1024*48;
    float* k2   = ws + off; off += (size_t)NB*1024*48;
    float* part1= ws + off; off += (size_t)32*NB*256*96;
    float* part2= ws + off; off += (size_t)8*NB*1024*96;
    float* V1   = ws + off; off += (size_t)NB*NTOK*48;
    float* V2   = ws + off; off += (size_t)NB*NTOK*48;
    if (ws_size < off*sizeof(float)) return;

    k_ln   <<<16384, 256, 0, stream>>>(x, norm_w, norm_b, nx);
    k_hgemm<<<2048, 256, 0, stream>>>(nx, Wh, bh, vbuf, gate);
    k_conv <<<512, 256, 0, stream>>>(nx, sr1_w, part1, 8, 4, 3, 6144);
    k_conv <<<512, 256, 0, stream>>>(nx, sr2_w, part2, 10, 5, 2, 1536);
    k_reduce<<<1024, 64, 0, stream>>>(part1, 32, 1024, sr1_b, n1_w, n1_b, Wqk, bqk, g1, be1, q1, k1);
    k_reduce<<<4096, 64, 0, stream>>>(part2, 8, 4096, sr2_b, n2_w, n2_b, Wqk, bqk, g2, be2, q2, k2);
    k_attn <<<512, 256, 0, stream>>>(vbuf, q1, k1, q2, k2, V1, V2);
    k_final<<<16384, 256, 0, stream>>>(V1, V2, gate, proj_w, proj_b, out);
}

// Round 5
// 425.195 us; speedup vs baseline: 3.8051x; 3.8051x over previous
//
#include <hip/hip_runtime.h>
#include <math.h>

#define NB   4
#define IH   128
#define IW   128
#define NTOK 16384        // IH*IW
#define CC   96
#define HID  192
#define QKD  48
#define EPSF 1e-5f
#define INV_N (1.0f/16384.0f)

typedef __attribute__((ext_vector_type(8))) short sh8;    // 8 bf16 (4 VGPRs)
typedef __attribute__((ext_vector_type(4))) float f32x4;  // 4 fp32

__device__ __forceinline__ float wave_sum64(float v){
    #pragma unroll
    for (int off = 32; off > 0; off >>= 1) v += __shfl_xor(v, off, 64);
    return v;
}
__device__ __forceinline__ float siluf(float x){ return x / (1.0f + expf(-x)); }
__device__ __forceinline__ float geluf(float x){ return 0.5f*x*(1.0f + erff(x*0.7071067811865475f)); }

__device__ __forceinline__ unsigned short f2bf(float f){   // RNE float->bf16 bits
    union { float f; unsigned u; } x; x.f = f;
    unsigned u = x.u + 0x7FFFu + ((x.u >> 16) & 1u);
    return (unsigned short)(u >> 16);
}
__device__ __forceinline__ unsigned pack2(float a, float b){
    return (unsigned)f2bf(a) | ((unsigned)f2bf(b) << 16);
}

// ---------------- 1. LayerNorm over C=96, wave per row ----------------
__global__ __launch_bounds__(256) void k_ln(const float* __restrict__ x,
                                            const float* __restrict__ w,
                                            const float* __restrict__ bb,
                                            float* __restrict__ nx){
    int row = blockIdx.x*4 + (threadIdx.x >> 6);
    int l = threadIdx.x & 63;
    const float* xr = x + (size_t)row*CC;
    float a = xr[l];
    float b = (l < 32) ? xr[64+l] : 0.0f;
    float s = wave_sum64(a + b);
    float m = s * (1.0f/96.0f);
    float d1 = a - m;
    float d2 = b - m;
    float sq = d1*d1 + ((l < 32) ? d2*d2 : 0.0f);
    float var = wave_sum64(sq) * (1.0f/96.0f);
    float rstd = rsqrtf(var + EPSF);
    float* o = nx + (size_t)row*CC;
    o[l] = d1*rstd*w[l] + bb[l];
    if (l < 32) o[64+l] = d2*rstd*w[64+l] + bb[64+l];
}

// ---------------- 2. h = silu(nx @ Wh + bh); split v/gate ----------------
__global__ __launch_bounds__(256) void k_hgemm(const float* __restrict__ nx,
                                               const float* __restrict__ Wh,
                                               const float* __restrict__ bh,
                                               float* __restrict__ vbuf,
                                               float* __restrict__ gate){
    __shared__ float xs[32*96];
    __shared__ float wt[192*36];   // wt[col][k] padded stride 36
    int tid = threadIdx.x;
    int row0 = blockIdx.x * 32;
    for (int i = tid; i < 32*96; i += 256)
        xs[i] = nx[(size_t)(row0 + i/96)*CC + (i%96)];
    int tc = tid & 31, tr = tid >> 5;
    float acc[4][6];
    #pragma unroll
    for (int i = 0; i < 4; i++)
        #pragma unroll
        for (int j = 0; j < 6; j++) acc[i][j] = 0.0f;

    for (int k0 = 0; k0 < 96; k0 += 32){
        __syncthreads();
        for (int idx = tid; idx < 32*192; idx += 256){
            int kk = idx / 192, col = idx % 192;
            wt[col*36 + kk] = Wh[(size_t)(k0+kk)*HID + col];
        }
        __syncthreads();
        #pragma unroll
        for (int k4 = 0; k4 < 8; k4++){
            float4 xa[4], wb[6];
            #pragma unroll
            for (int i = 0; i < 4; i++)
                xa[i] = *(const float4*)&xs[(tr*4+i)*96 + k0 + k4*4];
            #pragma unroll
            for (int j = 0; j < 6; j++)
                wb[j] = *(const float4*)&wt[(tc + j*32)*36 + k4*4];
            #pragma unroll
            for (int i = 0; i < 4; i++)
                #pragma unroll
                for (int j = 0; j < 6; j++){
                    acc[i][j] += xa[i].x*wb[j].x + xa[i].y*wb[j].y
                               + xa[i].z*wb[j].z + xa[i].w*wb[j].w;
                }
        }
    }
    #pragma unroll
    for (int i = 0; i < 4; i++){
        size_t row = row0 + tr*4 + i;
        #pragma unroll
        for (int j = 0; j < 6; j++){
            int col = tc + j*32;
            float hv = siluf(acc[i][j] + bh[col]);
            if (col < 96) vbuf[row*CC + col] = hv;
            else          gate[row*CC + col - 96] = hv;
        }
    }
}

// ---------------- 3. conv (patch GEMM, K-split) ----------------
__global__ __launch_bounds__(256) void k_conv(const float* __restrict__ nx,
                                              const float* __restrict__ wconv,
                                              float* __restrict__ part,
                                              int posLog, int pdimLog, int pszLog, int kTotal){
    __shared__ float pt[64*96];
    __shared__ float wt[96*100];
    int posPerImg = 1 << posLog;
    int pdim = 1 << pdimLog;
    int psz  = 1 << pszLog;
    int ksLog = 2*pszLog;
    int rowblocks = (NB << posLog) >> 6;
    int rb = blockIdx.x % rowblocks;
    int split = blockIdx.x / rowblocks;
    int tid = threadIdx.x;
    int to = tid & 15, ty = tid >> 4;
    float acc[4][6];
    #pragma unroll
    for (int i = 0; i < 4; i++)
        #pragma unroll
        for (int j = 0; j < 6; j++) acc[i][j] = 0.0f;

    for (int half = 0; half < 2; half++){
        int kb = split*192 + half*96;
        __syncthreads();
        for (int idx = tid; idx < 96*96; idx += 256){
            int o = idx / 96, kk = idx % 96;
            wt[o*100 + kk] = wconv[(size_t)o*kTotal + kb + kk];
        }
        for (int idx = tid; idx < 64*96; idx += 256){
            int r = idx / 96, kk = idx % 96;
            int R = rb*64 + r;
            int b = R >> posLog, p = R & (posPerImg-1);
            int k = kb + kk;
            int c = k >> ksLog, s = k & ((psz*psz)-1);
            int pi = p >> pdimLog, pj = p & (pdim-1);
            int px = (pi << pszLog) + (s >> pszLog);
            int py = (pj << pszLog) + (s & (psz-1));
            pt[r*96 + kk] = nx[((size_t)b*NTOK + px*IW + py)*CC + c];
        }
        __syncthreads();
        #pragma unroll 4
        for (int k4 = 0; k4 < 24; k4++){
            float4 xa[4], wb[6];
            #pragma unroll
            for (int i = 0; i < 4; i++)
                xa[i] = *(const float4*)&pt[(ty*4+i)*96 + k4*4];
            #pragma unroll
            for (int j = 0; j < 6; j++)
                wb[j] = *(const float4*)&wt[(to + j*16)*100 + k4*4];
            #pragma unroll
            for (int i = 0; i < 4; i++)
                #pragma unroll
                for (int j = 0; j < 6; j++){
                    acc[i][j] += xa[i].x*wb[j].x + xa[i].y*wb[j].y
                               + xa[i].z*wb[j].z + xa[i].w*wb[j].w;
                }
        }
    }
    int rowsTotal = NB << posLog;
    #pragma unroll
    for (int i = 0; i < 4; i++){
        int R = rb*64 + ty*4 + i;
        #pragma unroll
        for (int j = 0; j < 6; j++){
            int o = to + j*16;
            part[((size_t)split*rowsTotal + R)*96 + o] = acc[i][j];
        }
    }
}

// ---------------- 4. reduce K-splits + bias + LN + gelu + Z/q/k ----------------
__global__ __launch_bounds__(64) void k_reduce(const float* __restrict__ part,
                                               int nsplit, int rows,
                                               const float* __restrict__ cbias,
                                               const float* __restrict__ lw,
                                               const float* __restrict__ lb,
                                               const float* __restrict__ wqk,
                                               const float* __restrict__ bqk,
                                               const float* __restrict__ g,
                                               const float* __restrict__ be,
                                               float* __restrict__ qout,
                                               float* __restrict__ kout){
    __shared__ float xsh[96];
    int row = blockIdx.x;
    int l = threadIdx.x;
    float y1 = 0.0f, y2 = 0.0f;
    for (int s = 0; s < nsplit; s++){
        const float* pr = part + ((size_t)s*rows + row)*96;
        y1 += pr[l];
        if (l < 32) y2 += pr[64+l];
    }
    y1 += cbias[l];
    if (l < 32) y2 += cbias[64+l];
    float s = wave_sum64(y1 + ((l < 32) ? y2 : 0.0f));
    float m = s * (1.0f/96.0f);
    float d1 = y1 - m, d2 = y2 - m;
    float var = wave_sum64(d1*d1 + ((l < 32) ? d2*d2 : 0.0f)) * (1.0f/96.0f);
    float rstd = rsqrtf(var + EPSF);
    xsh[l] = geluf(d1*rstd*lw[l] + lb[l]);
    if (l < 32) xsh[64+l] = geluf(d2*rstd*lw[64+l] + lb[64+l]);
    __syncthreads();
    if (l < 48){
        float z = bqk[l];
        #pragma unroll 4
        for (int c = 0; c < 96; c++) z += xsh[c]*wqk[c*48 + l];
        z = siluf(z);
        qout[(size_t)row*48 + l] = z*g[l]    + be[l];
        kout[(size_t)row*48 + l] = z*g[48+l] + be[48+l];
    }
}

// ---------------- 5. attention via bf16 MFMA ----------------
// Block = 64 rows, 4 waves x 16 rows. Per 32-m chunk:
//   GEMM1: S[16n x 32m] = v . q^T  (2 m-subtiles x 2 k-chunks of mfma_16x16x32_bf16, d=48 padded to 64)
//   P = relu(S/N)^2 in fp32, round-trip via wave-private LDS tile [16][36]
//   GEMM2: O[16n x 48d] += P . k    (3 d-subtiles, K=32)
// A- and B-fragments both use contiguous-8 k-sourcing -> result invariant to the
// intra-operand k permutation. C/D layout: col=lane&15, row=(lane>>4)*4+reg (m89-verified).
__global__ __launch_bounds__(256) void k_attn(const float* __restrict__ vbuf,
                                              const float* __restrict__ q1,
                                              const float* __restrict__ k1,
                                              const float* __restrict__ q2,
                                              const float* __restrict__ k2,
                                              float* __restrict__ V1,
                                              float* __restrict__ V2){
    __shared__ unsigned short qbf[32*72];   // q[m][d] bf16, d padded to 64 (stride 72 anti-conflict)
    __shared__ unsigned short ktbf[48*40];  // k^T[d][m] bf16 (stride 40)
    __shared__ float Pl[4][16*36];          // per-wave P tile [16n][32m] (stride 36)

    int bx   = blockIdx.x;
    int kind = bx >> 10;                 // 0: branch1 (M=256), 1: branch2 (M=1024)
    int blk  = bx & 1023;
    int tid  = threadIdx.x;
    int wid  = tid >> 6;
    int lane = tid & 63;
    int lo   = lane & 15;
    int g    = lane >> 4;
    int row0 = blk*64 + wid*16;          // wave's first global row (0..65535)
    int b    = row0 >> 14;               // batch

    const float* qsrc = kind ? q2 + (size_t)b*1024*48 : q1 + (size_t)b*256*48;
    const float* ksrc = kind ? k2 + (size_t)b*1024*48 : k1 + (size_t)b*256*48;
    int   M     = kind ? 1024 : 256;
    int   voff  = kind ? 48 : 0;
    float* vout = kind ? V2 : V1;

    // zero the q_bf pad region d in [48,64) once (never re-dirtied)
    {
        int m = tid >> 3, j = tid & 7;
        *(unsigned*)&qbf[m*72 + 48 + j*2] = 0u;
    }

    // v A-fragments (per-wave resident): lane holds v[row0+lo][d], d = kc*32 + g*8 .. +7
    sh8 va[2];
    {
        const float* vrow = vbuf + (size_t)(row0 + lo)*CC + voff;
        union { unsigned u[4]; sh8 v; } pk;
        f32x4 a0 = *(const f32x4*)(vrow + g*8);
        f32x4 a1 = *(const f32x4*)(vrow + g*8 + 4);
        pk.u[0] = pack2(a0[0], a0[1]); pk.u[1] = pack2(a0[2], a0[3]);
        pk.u[2] = pack2(a1[0], a1[1]); pk.u[3] = pack2(a1[2], a1[3]);
        va[0] = pk.v;
        if (g < 2){
            f32x4 b0 = *(const f32x4*)(vrow + 32 + g*8);
            f32x4 b1 = *(const f32x4*)(vrow + 32 + g*8 + 4);
            pk.u[0] = pack2(b0[0], b0[1]); pk.u[1] = pack2(b0[2], b0[3]);
            pk.u[2] = pack2(b1[0], b1[1]); pk.u[3] = pack2(b1[2], b1[3]);
        } else {
            pk.u[0] = 0u; pk.u[1] = 0u; pk.u[2] = 0u; pk.u[3] = 0u;
        }
        va[1] = pk.v;
    }

    // per-thread staging index split (constant across chunks)
    int stm[6], qo[6], ko[6];
    #pragma unroll
    for (int it = 0; it < 6; it++){
        int idx = tid + it*256;          // 0..1535 over [32m][48d]
        int m = idx / 48, d = idx - m*48;
        stm[it] = m;
        qo[it]  = m*72 + d;              // q_bf[m][d]
        ko[it]  = d*40 + m;              // kT[d][m]
    }

    f32x4 acc[3];
    acc[0] = (f32x4){0.f,0.f,0.f,0.f};
    acc[1] = (f32x4){0.f,0.f,0.f,0.f};
    acc[2] = (f32x4){0.f,0.f,0.f,0.f};

    int nchunk = M >> 5;
    float* Pw = Pl[wid];

    for (int ch = 0; ch < nchunk; ch++){
        int mb = ch*32;
        __syncthreads();                 // protect LDS reuse (WAR) + join staging
        #pragma unroll
        for (int it = 0; it < 6; it++){
            int idx = tid + it*256;
            qbf[qo[it]]  = f2bf(qsrc[(size_t)mb*48 + idx]);
            ktbf[ko[it]] = f2bf(ksrc[(size_t)mb*48 + idx]);
        }
        __syncthreads();

        // ---- GEMM1 + relu^2 -> P ----
        #pragma unroll
        for (int mt = 0; mt < 2; mt++){
            f32x4 c = (f32x4){0.f,0.f,0.f,0.f};
            #pragma unroll
            for (int kc = 0; kc < 2; kc++){
                sh8 bq = *(const sh8*)&qbf[(mt*16 + lo)*72 + kc*32 + g*8];
                c = __builtin_amdgcn_mfma_f32_16x16x32_bf16(va[kc], bq, c, 0, 0, 0);
            }
            #pragma unroll
            for (int j = 0; j < 4; j++){
                float s = c[j] * INV_N;
                s = fmaxf(s, 0.f);
                Pw[(g*4 + j)*36 + mt*16 + lo] = s*s;
            }
        }

        // ---- GEMM2: acc += P . k ----
        sh8 pa;
        {
            f32x4 p0 = *(const f32x4*)&Pw[lo*36 + g*8];
            f32x4 p1 = *(const f32x4*)&Pw[lo*36 + g*8 + 4];
            union { unsigned u[4]; sh8 v; } pk;
            pk.u[0] = pack2(p0[0], p0[1]); pk.u[1] = pack2(p0[2], p0[3]);
            pk.u[2] = pack2(p1[0], p1[1]); pk.u[3] = pack2(p1[2], p1[3]);
            pa = pk.v;
        }
        #pragma unroll
        for (int dt = 0; dt < 3; dt++){
            sh8 bk = *(const sh8*)&ktbf[(dt*16 + lo)*40 + g*8];
            acc[dt] = __builtin_amdgcn_mfma_f32_16x16x32_bf16(pa, bk, acc[dt], 0, 0, 0);
        }
    }

    // ---- write O: row = row0 + g*4 + j, col = dt*16 + lo ----
    #pragma unroll
    for (int dt = 0; dt < 3; dt++)
        #pragma unroll
        for (int j = 0; j < 4; j++)
            vout[(size_t)(row0 + g*4 + j)*48 + dt*16 + lo] = acc[dt][j];
}

// ---------------- 6. final: xc, gate, proj, residual ----------------
__global__ __launch_bounds__(256) void k_final(const float* __restrict__ V1,
                                               const float* __restrict__ V2,
                                               const float* __restrict__ gate,
                                               const float* __restrict__ projw,
                                               const float* __restrict__ projb,
                                               float* __restrict__ out){
    __shared__ float pj[96*96];
    __shared__ float vsh[4][96];
    int tid = threadIdx.x;
    for (int i = tid; i < 96*96; i += 256) pj[i] = projw[i];
    int w = tid >> 6, l = tid & 63;
    size_t row = (size_t)blockIdx.x*4 + w;

    float xc1 = (l < 48) ? V1[row*48 + l] : V2[row*48 + (l-48)];
    float xc2 = 0.0f;
    if (l < 32) xc2 = V2[row*48 + 16 + l];
    float ga = gate[row*CC + l];
    float gb = (l < 32) ? gate[row*CC + 64 + l] : 0.0f;
    vsh[w][l] = xc1*ga;
    if (l < 32) vsh[w][64+l] = xc2*gb;
    __syncthreads();

    float a0 = projb[l];
    float a1 = (l < 32) ? projb[64+l] : 0.0f;
    #pragma unroll 4
    for (int c = 0; c < 96; c++){
        float vv = vsh[w][c];
        a0 += vv*pj[c*96 + l];
        if (l < 32) a1 += vv*pj[c*96 + 64 + l];
    }
    out[row*CC + l] = a0 + xc1;
    if (l < 32) out[row*CC + 64 + l] = a1 + xc2;
}

extern "C" void kernel_launch(void* const* d_in, const int* in_sizes, int n_in,
                              void* d_out, int out_size, void* d_ws, size_t ws_size,
                              hipStream_t stream){
    const float* x      = (const float*)d_in[0];
    const float* norm_w = (const float*)d_in[3];
    const float* norm_b = (const float*)d_in[4];
    const float* Wh     = (const float*)d_in[5];
    const float* bh     = (const float*)d_in[6];
    const float* Wqk    = (const float*)d_in[7];
    const float* bqk    = (const float*)d_in[8];
    const float* g1     = (const float*)d_in[9];
    const float* be1    = (const float*)d_in[10];
    const float* g2     = (const float*)d_in[11];
    const float* be2    = (const float*)d_in[12];
    const float* sr1_w  = (const float*)d_in[13];
    const float* sr1_b  = (const float*)d_in[14];
    const float* sr2_w  = (const float*)d_in[15];
    const float* sr2_b  = (const float*)d_in[16];
    const float* n1_w   = (const float*)d_in[17];
    const float* n1_b   = (const float*)d_in[18];
    const float* n2_w   = (const float*)d_in[19];
    const float* n2_b   = (const float*)d_in[20];
    const float* proj_w = (const float*)d_in[21];
    const float* proj_b = (const float*)d_in[22];
    float* out = (float*)d_out;

    float* ws = (float*)d_ws;
    size_t off = 0;
    float* nx   = ws + off; off += (size_t)NB*NTOK*CC;
    float* vbuf = ws + off; off += (size_t)NB*NTOK*CC;
    float* gate = ws + off; off += (size_t)NB*NTOK*CC;
    float* q1   = ws + off; off += (size_t)NB*256*48;
    float* k1   = ws + off; off += (size_t)NB*256*48;
    float* q2   = ws + off; off += (size_t)NB*1024*48;
    float* k2   = ws + off; off += (size_t)NB*1024*48;
    float* part1= ws + off; off += (size_t)32*NB*256*96;
    float* part2= ws + off; off += (size_t)8*NB*1024*96;
    float* V1   = ws + off; off += (size_t)NB*NTOK*48;
    float* V2   = ws + off; off += (size_t)NB*NTOK*48;
    if (ws_size < off*sizeof(float)) return;

    k_ln   <<<16384, 256, 0, stream>>>(x, norm_w, norm_b, nx);
    k_hgemm<<<2048, 256, 0, stream>>>(nx, Wh, bh, vbuf, gate);
    k_conv <<<512, 256, 0, stream>>>(nx, sr1_w, part1, 8, 4, 3, 6144);
    k_conv <<<512, 256, 0, stream>>>(nx, sr2_w, part2, 10, 5, 2, 1536);
    k_reduce<<<1024, 64, 0, stream>>>(part1, 32, 1024, sr1_b, n1_w, n1_b, Wqk, bqk, g1, be1, q1, k1);
    k_reduce<<<4096, 64, 0, stream>>>(part2, 8, 4096, sr2_b, n2_w, n2_b, Wqk, bqk, g2, be2, q2, k2);
    k_attn <<<2048, 256, 0, stream>>>(vbuf, q1, k1, q2, k2, V1, V2);
    k_final<<<16384, 256, 0, stream>>>(V1, V2, gate, proj_w, proj_b, out);
}

// Round 6
// 320.067 us; speedup vs baseline: 5.0549x; 1.3285x over previous
//
#include <hip/hip_runtime.h>
#include <math.h>

#define NB   4
#define IH   128
#define IW   128
#define NTOK 16384        // IH*IW
#define CC   96
#define HID  192
#define QKD  48
#define EPSF 1e-5f
#define INV_N (1.0f/16384.0f)

typedef __attribute__((ext_vector_type(8))) short sh8;    // 8 bf16 (4 VGPRs)
typedef __attribute__((ext_vector_type(4))) float f32x4;  // 4 fp32

__device__ __forceinline__ float wave_sum64(float v){
    #pragma unroll
    for (int off = 32; off > 0; off >>= 1) v += __shfl_xor(v, off, 64);
    return v;
}
__device__ __forceinline__ float siluf(float x){ return x / (1.0f + __expf(-x)); }
__device__ __forceinline__ float geluf(float x){ return 0.5f*x*(1.0f + erff(x*0.7071067811865475f)); }

__device__ __forceinline__ unsigned short f2bf(float f){   // RNE float->bf16 bits
    union { float f; unsigned u; } x; x.f = f;
    unsigned u = x.u + 0x7FFFu + ((x.u >> 16) & 1u);
    return (unsigned short)(u >> 16);
}
__device__ __forceinline__ unsigned pack2(float a, float b){
    return (unsigned)f2bf(a) | ((unsigned)f2bf(b) << 16);
}

// ---------------- 1. LayerNorm over C=96, wave per row ----------------
__global__ __launch_bounds__(256) void k_ln(const float* __restrict__ x,
                                            const float* __restrict__ w,
                                            const float* __restrict__ bb,
                                            float* __restrict__ nx){
    int row = blockIdx.x*4 + (threadIdx.x >> 6);
    int l = threadIdx.x & 63;
    const float* xr = x + (size_t)row*CC;
    float a = xr[l];
    float b = (l < 32) ? xr[64+l] : 0.0f;
    float s = wave_sum64(a + b);
    float m = s * (1.0f/96.0f);
    float d1 = a - m;
    float d2 = b - m;
    float sq = d1*d1 + ((l < 32) ? d2*d2 : 0.0f);
    float var = wave_sum64(sq) * (1.0f/96.0f);
    float rstd = rsqrtf(var + EPSF);
    float* o = nx + (size_t)row*CC;
    o[l] = d1*rstd*w[l] + bb[l];
    if (l < 32) o[64+l] = d2*rstd*w[64+l] + bb[64+l];
}

// ---------------- 2. h = silu(nx @ Wh + bh) via bf16 MFMA; split v/gate ----------------
// Block = 64 rows (4 waves x 16 rows), full N=192 per wave. Wh staged once as bf16
// LDS tile [192 cols][96 k] stride 100 (<=2-way banks). A = nx rows packed to bf16.
// Fragment conventions identical to the validated k_attn: A lane-lo<->row, k=kc*32+g*8;
// B lane-lo<->col; D element j at (row g*4+j, col lo).
__global__ __launch_bounds__(256) void k_hgemm(const float* __restrict__ nx,
                                               const float* __restrict__ Wh,
                                               const float* __restrict__ bh,
                                               float* __restrict__ vbuf,
                                               float* __restrict__ gate){
    __shared__ unsigned short whbf[192*100];   // [col][k] bf16, stride 100
    int tid  = threadIdx.x;
    int lane = tid & 63;
    int wid  = tid >> 6;
    int lo   = lane & 15;
    int g    = lane >> 4;
    int row0 = blockIdx.x*64 + wid*16;

    // stage Wh (96x192 fp32, row-major [k][col]) -> whbf[col][k]
    #pragma unroll
    for (int it = 0; it < 72; it++){
        int idx = tid + it*256;          // 0..18431
        int k = idx / 192, col = idx - k*192;
        whbf[col*100 + k] = f2bf(Wh[idx]);
    }

    // A-fragments: lane holds nx[row0+lo][kc*32 + g*8 .. +7]
    sh8 a[3];
    {
        const float* ar = nx + (size_t)(row0 + lo)*CC;
        #pragma unroll
        for (int kc = 0; kc < 3; kc++){
            f32x4 x0 = *(const f32x4*)(ar + kc*32 + g*8);
            f32x4 x1 = *(const f32x4*)(ar + kc*32 + g*8 + 4);
            union { unsigned u[4]; sh8 v; } pk;
            pk.u[0] = pack2(x0[0], x0[1]); pk.u[1] = pack2(x0[2], x0[3]);
            pk.u[2] = pack2(x1[0], x1[1]); pk.u[3] = pack2(x1[2], x1[3]);
            a[kc] = pk.v;
        }
    }
    __syncthreads();

    f32x4 acc[12];
    #pragma unroll
    for (int ct = 0; ct < 12; ct++) acc[ct] = (f32x4){0.f,0.f,0.f,0.f};
    #pragma unroll
    for (int ct = 0; ct < 12; ct++){
        #pragma unroll
        for (int kc = 0; kc < 3; kc++){
            sh8 bw = *(const sh8*)&whbf[(ct*16 + lo)*100 + kc*32 + g*8];
            acc[ct] = __builtin_amdgcn_mfma_f32_16x16x32_bf16(a[kc], bw, acc[ct], 0, 0, 0);
        }
    }

    // epilogue: silu(+bias), split v/gate. row = row0+g*4+j, col = ct*16+lo
    #pragma unroll
    for (int ct = 0; ct < 12; ct++){
        int col = ct*16 + lo;
        float bcol = bh[col];
        #pragma unroll
        for (int j = 0; j < 4; j++){
            size_t row = row0 + g*4 + j;
            float hv = siluf(acc[ct][j] + bcol);
            if (col < 96) vbuf[row*CC + col] = hv;
            else          gate[row*CC + col - 96] = hv;
        }
    }
}

// ---------------- 3. conv (patch GEMM, K-split) ----------------
__global__ __launch_bounds__(256) void k_conv(const float* __restrict__ nx,
                                              const float* __restrict__ wconv,
                                              float* __restrict__ part,
                                              int posLog, int pdimLog, int pszLog, int kTotal){
    __shared__ float pt[64*96];
    __shared__ float wt[96*100];
    int posPerImg = 1 << posLog;
    int pdim = 1 << pdimLog;
    int psz  = 1 << pszLog;
    int ksLog = 2*pszLog;
    int rowblocks = (NB << posLog) >> 6;
    int rb = blockIdx.x % rowblocks;
    int split = blockIdx.x / rowblocks;
    int tid = threadIdx.x;
    int to = tid & 15, ty = tid >> 4;
    float acc[4][6];
    #pragma unroll
    for (int i = 0; i < 4; i++)
        #pragma unroll
        for (int j = 0; j < 6; j++) acc[i][j] = 0.0f;

    for (int half = 0; half < 2; half++){
        int kb = split*192 + half*96;
        __syncthreads();
        for (int idx = tid; idx < 96*96; idx += 256){
            int o = idx / 96, kk = idx % 96;
            wt[o*100 + kk] = wconv[(size_t)o*kTotal + kb + kk];
        }
        for (int idx = tid; idx < 64*96; idx += 256){
            int r = idx / 96, kk = idx % 96;
            int R = rb*64 + r;
            int b = R >> posLog, p = R & (posPerImg-1);
            int k = kb + kk;
            int c = k >> ksLog, s = k & ((psz*psz)-1);
            int pi = p >> pdimLog, pj = p & (pdim-1);
            int px = (pi << pszLog) + (s >> pszLog);
            int py = (pj << pszLog) + (s & (psz-1));
            pt[r*96 + kk] = nx[((size_t)b*NTOK + px*IW + py)*CC + c];
        }
        __syncthreads();
        #pragma unroll 4
        for (int k4 = 0; k4 < 24; k4++){
            float4 xa[4], wb[6];
            #pragma unroll
            for (int i = 0; i < 4; i++)
                xa[i] = *(const float4*)&pt[(ty*4+i)*96 + k4*4];
            #pragma unroll
            for (int j = 0; j < 6; j++)
                wb[j] = *(const float4*)&wt[(to + j*16)*100 + k4*4];
            #pragma unroll
            for (int i = 0; i < 4; i++)
                #pragma unroll
                for (int j = 0; j < 6; j++){
                    acc[i][j] += xa[i].x*wb[j].x + xa[i].y*wb[j].y
                               + xa[i].z*wb[j].z + xa[i].w*wb[j].w;
                }
        }
    }
    int rowsTotal = NB << posLog;
    #pragma unroll
    for (int i = 0; i < 4; i++){
        int R = rb*64 + ty*4 + i;
        #pragma unroll
        for (int j = 0; j < 6; j++){
            int o = to + j*16;
            part[((size_t)split*rowsTotal + R)*96 + o] = acc[i][j];
        }
    }
}

// ---------------- 4. reduce K-splits + bias + LN + gelu + Z/q/k ----------------
__global__ __launch_bounds__(64) void k_reduce(const float* __restrict__ part,
                                               int nsplit, int rows,
                                               const float* __restrict__ cbias,
                                               const float* __restrict__ lw,
                                               const float* __restrict__ lb,
                                               const float* __restrict__ wqk,
                                               const float* __restrict__ bqk,
                                               const float* __restrict__ g,
                                               const float* __restrict__ be,
                                               float* __restrict__ qout,
                                               float* __restrict__ kout){
    __shared__ float xsh[96];
    int row = blockIdx.x;
    int l = threadIdx.x;
    float y1 = 0.0f, y2 = 0.0f;
    for (int s = 0; s < nsplit; s++){
        const float* pr = part + ((size_t)s*rows + row)*96;
        y1 += pr[l];
        if (l < 32) y2 += pr[64+l];
    }
    y1 += cbias[l];
    if (l < 32) y2 += cbias[64+l];
    float s = wave_sum64(y1 + ((l < 32) ? y2 : 0.0f));
    float m = s * (1.0f/96.0f);
    float d1 = y1 - m, d2 = y2 - m;
    float var = wave_sum64(d1*d1 + ((l < 32) ? d2*d2 : 0.0f)) * (1.0f/96.0f);
    float rstd = rsqrtf(var + EPSF);
    xsh[l] = geluf(d1*rstd*lw[l] + lb[l]);
    if (l < 32) xsh[64+l] = geluf(d2*rstd*lw[64+l] + lb[64+l]);
    __syncthreads();
    if (l < 48){
        float z = bqk[l];
        #pragma unroll 4
        for (int c = 0; c < 96; c++) z += xsh[c]*wqk[c*48 + l];
        z = siluf(z);
        qout[(size_t)row*48 + l] = z*g[l]    + be[l];
        kout[(size_t)row*48 + l] = z*g[48+l] + be[48+l];
    }
}

// ---------------- 5. attention via bf16 MFMA ----------------
__global__ __launch_bounds__(256) void k_attn(const float* __restrict__ vbuf,
                                              const float* __restrict__ q1,
                                              const float* __restrict__ k1,
                                              const float* __restrict__ q2,
                                              const float* __restrict__ k2,
                                              float* __restrict__ V1,
                                              float* __restrict__ V2){
    __shared__ unsigned short qbf[32*72];   // q[m][d] bf16, d padded to 64 (stride 72)
    __shared__ unsigned short ktbf[48*40];  // k^T[d][m] bf16 (stride 40)
    __shared__ float Pl[4][16*36];          // per-wave P tile [16n][32m] (stride 36)

    int bx   = blockIdx.x;
    int kind = bx >> 10;                 // 0: branch1 (M=256), 1: branch2 (M=1024)
    int blk  = bx & 1023;
    int tid  = threadIdx.x;
    int wid  = tid >> 6;
    int lane = tid & 63;
    int lo   = lane & 15;
    int g    = lane >> 4;
    int row0 = blk*64 + wid*16;          // wave's first global row (0..65535)
    int b    = row0 >> 14;               // batch

    const float* qsrc = kind ? q2 + (size_t)b*1024*48 : q1 + (size_t)b*256*48;
    const float* ksrc = kind ? k2 + (size_t)b*1024*48 : k1 + (size_t)b*256*48;
    int   M     = kind ? 1024 : 256;
    int   voff  = kind ? 48 : 0;
    float* vout = kind ? V2 : V1;

    // zero the q_bf pad region d in [48,64) once (never re-dirtied)
    {
        int m = tid >> 3, j = tid & 7;
        *(unsigned*)&qbf[m*72 + 48 + j*2] = 0u;
    }

    // v A-fragments (per-wave resident): lane holds v[row0+lo][d], d = kc*32 + g*8 .. +7
    sh8 va[2];
    {
        const float* vrow = vbuf + (size_t)(row0 + lo)*CC + voff;
        union { unsigned u[4]; sh8 v; } pk;
        f32x4 a0 = *(const f32x4*)(vrow + g*8);
        f32x4 a1 = *(const f32x4*)(vrow + g*8 + 4);
        pk.u[0] = pack2(a0[0], a0[1]); pk.u[1] = pack2(a0[2], a0[3]);
        pk.u[2] = pack2(a1[0], a1[1]); pk.u[3] = pack2(a1[2], a1[3]);
        va[0] = pk.v;
        if (g < 2){
            f32x4 b0 = *(const f32x4*)(vrow + 32 + g*8);
            f32x4 b1 = *(const f32x4*)(vrow + 32 + g*8 + 4);
            pk.u[0] = pack2(b0[0], b0[1]); pk.u[1] = pack2(b0[2], b0[3]);
            pk.u[2] = pack2(b1[0], b1[1]); pk.u[3] = pack2(b1[2], b1[3]);
        } else {
            pk.u[0] = 0u; pk.u[1] = 0u; pk.u[2] = 0u; pk.u[3] = 0u;
        }
        va[1] = pk.v;
    }

    // per-thread staging index split (constant across chunks)
    int qo[6], ko[6];
    #pragma unroll
    for (int it = 0; it < 6; it++){
        int idx = tid + it*256;          // 0..1535 over [32m][48d]
        int m = idx / 48, d = idx - m*48;
        qo[it]  = m*72 + d;              // q_bf[m][d]
        ko[it]  = d*40 + m;              // kT[d][m]
    }

    f32x4 acc[3];
    acc[0] = (f32x4){0.f,0.f,0.f,0.f};
    acc[1] = (f32x4){0.f,0.f,0.f,0.f};
    acc[2] = (f32x4){0.f,0.f,0.f,0.f};

    int nchunk = M >> 5;
    float* Pw = Pl[wid];

    for (int ch = 0; ch < nchunk; ch++){
        int mb = ch*32;
        __syncthreads();                 // protect LDS reuse (WAR) + join staging
        #pragma unroll
        for (int it = 0; it < 6; it++){
            int idx = tid + it*256;
            qbf[qo[it]]  = f2bf(qsrc[(size_t)mb*48 + idx]);
            ktbf[ko[it]] = f2bf(ksrc[(size_t)mb*48 + idx]);
        }
        __syncthreads();

        // ---- GEMM1 + relu^2 -> P ----
        #pragma unroll
        for (int mt = 0; mt < 2; mt++){
            f32x4 c = (f32x4){0.f,0.f,0.f,0.f};
            #pragma unroll
            for (int kc = 0; kc < 2; kc++){
                sh8 bq = *(const sh8*)&qbf[(mt*16 + lo)*72 + kc*32 + g*8];
                c = __builtin_amdgcn_mfma_f32_16x16x32_bf16(va[kc], bq, c, 0, 0, 0);
            }
            #pragma unroll
            for (int j = 0; j < 4; j++){
                float s = c[j] * INV_N;
                s = fmaxf(s, 0.f);
                Pw[(g*4 + j)*36 + mt*16 + lo] = s*s;
            }
        }

        // ---- GEMM2: acc += P . k ----
        sh8 pa;
        {
            f32x4 p0 = *(const f32x4*)&Pw[lo*36 + g*8];
            f32x4 p1 = *(const f32x4*)&Pw[lo*36 + g*8 + 4];
            union { unsigned u[4]; sh8 v; } pk;
            pk.u[0] = pack2(p0[0], p0[1]); pk.u[1] = pack2(p0[2], p0[3]);
            pk.u[2] = pack2(p1[0], p1[1]); pk.u[3] = pack2(p1[2], p1[3]);
            pa = pk.v;
        }
        #pragma unroll
        for (int dt = 0; dt < 3; dt++){
            sh8 bk = *(const sh8*)&ktbf[(dt*16 + lo)*40 + g*8];
            acc[dt] = __builtin_amdgcn_mfma_f32_16x16x32_bf16(pa, bk, acc[dt], 0, 0, 0);
        }
    }

    // ---- write O: row = row0 + g*4 + j, col = dt*16 + lo ----
    #pragma unroll
    for (int dt = 0; dt < 3; dt++)
        #pragma unroll
        for (int j = 0; j < 4; j++)
            vout[(size_t)(row0 + g*4 + j)*48 + dt*16 + lo] = acc[dt][j];
}

// ---------------- 6. final: xc, gate, proj, residual ----------------
__global__ __launch_bounds__(256) void k_final(const float* __restrict__ V1,
                                               const float* __restrict__ V2,
                                               const float* __restrict__ gate,
                                               const float* __restrict__ projw,
                                               const float* __restrict__ projb,
                                               float* __restrict__ out){
    __shared__ float pj[96*96];
    __shared__ float vsh[4][96];
    int tid = threadIdx.x;
    for (int i = tid; i < 96*96; i += 256) pj[i] = projw[i];
    int w = tid >> 6, l = tid & 63;
    size_t row = (size_t)blockIdx.x*4 + w;

    float xc1 = (l < 48) ? V1[row*48 + l] : V2[row*48 + (l-48)];
    float xc2 = 0.0f;
    if (l < 32) xc2 = V2[row*48 + 16 + l];
    float ga = gate[row*CC + l];
    float gb = (l < 32) ? gate[row*CC + 64 + l] : 0.0f;
    vsh[w][l] = xc1*ga;
    if (l < 32) vsh[w][64+l] = xc2*gb;
    __syncthreads();

    float a0 = projb[l];
    float a1 = (l < 32) ? projb[64+l] : 0.0f;
    #pragma unroll 4
    for (int c = 0; c < 96; c++){
        float vv = vsh[w][c];
        a0 += vv*pj[c*96 + l];
        if (l < 32) a1 += vv*pj[c*96 + 64 + l];
    }
    out[row*CC + l] = a0 + xc1;
    if (l < 32) out[row*CC + 64 + l] = a1 + xc2;
}

extern "C" void kernel_launch(void* const* d_in, const int* in_sizes, int n_in,
                              void* d_out, int out_size, void* d_ws, size_t ws_size,
                              hipStream_t stream){
    const float* x      = (const float*)d_in[0];
    const float* norm_w = (const float*)d_in[3];
    const float* norm_b = (const float*)d_in[4];
    const float* Wh     = (const float*)d_in[5];
    const float* bh     = (const float*)d_in[6];
    const float* Wqk    = (const float*)d_in[7];
    const float* bqk    = (const float*)d_in[8];
    const float* g1     = (const float*)d_in[9];
    const float* be1    = (const float*)d_in[10];
    const float* g2     = (const float*)d_in[11];
    const float* be2    = (const float*)d_in[12];
    const float* sr1_w  = (const float*)d_in[13];
    const float* sr1_b  = (const float*)d_in[14];
    const float* sr2_w  = (const float*)d_in[15];
    const float* sr2_b  = (const float*)d_in[16];
    const float* n1_w   = (const float*)d_in[17];
    const float* n1_b   = (const float*)d_in[18];
    const float* n2_w   = (const float*)d_in[19];
    const float* n2_b   = (const float*)d_in[20];
    const float* proj_w = (const float*)d_in[21];
    const float* proj_b = (const float*)d_in[22];
    float* out = (float*)d_out;

    float* ws = (float*)d_ws;
    size_t off = 0;
    float* nx   = ws + off; off += (size_t)NB*NTOK*CC;
    float* vbuf = ws + off; off += (size_t)NB*NTOK*CC;
    float* gate = ws + off; off += (size_t)NB*NTOK*CC;
    float* q1   = ws + off; off += (size_t)NB*256*48;
    float* k1   = ws + off; off += (size_t)NB*256*48;
    float* q2   = ws + off; off += (size_t)NB*1024*48;
    float* k2   = ws + off; off += (size_t)NB*1024*48;
    float* part1= ws + off; off += (size_t)32*NB*256*96;
    float* part2= ws + off; off += (size_t)8*NB*1024*96;
    float* V1   = ws + off; off += (size_t)NB*NTOK*48;
    float* V2   = ws + off; off += (size_t)NB*NTOK*48;
    if (ws_size < off*sizeof(float)) return;

    k_ln   <<<16384, 256, 0, stream>>>(x, norm_w, norm_b, nx);
    k_hgemm<<<1024, 256, 0, stream>>>(nx, Wh, bh, vbuf, gate);
    k_conv <<<512, 256, 0, stream>>>(nx, sr1_w, part1, 8, 4, 3, 6144);
    k_conv <<<512, 256, 0, stream>>>(nx, sr2_w, part2, 10, 5, 2, 1536);
    k_reduce<<<1024, 64, 0, stream>>>(part1, 32, 1024, sr1_b, n1_w, n1_b, Wqk, bqk, g1, be1, q1, k1);
    k_reduce<<<4096, 64, 0, stream>>>(part2, 8, 4096, sr2_b, n2_w, n2_b, Wqk, bqk, g2, be2, q2, k2);
    k_attn <<<2048, 256, 0, stream>>>(vbuf, q1, k1, q2, k2, V1, V2);
    k_final<<<16384, 256, 0, stream>>>(V1, V2, gate, proj_w, proj_b, out);
}

// Round 7
// 222.961 us; speedup vs baseline: 7.2565x; 1.4355x over previous
//
#include <hip/hip_runtime.h>
#include <math.h>

#define NB   4
#define IH   128
#define IW   128
#define NTOK 16384        // IH*IW
#define CC   96
#define HID  192
#define QKD  48
#define EPSF 1e-5f
#define INV_N (1.0f/16384.0f)

typedef __attribute__((ext_vector_type(8))) short sh8;    // 8 bf16 (4 VGPRs)
typedef __attribute__((ext_vector_type(4))) float f32x4;  // 4 fp32

__device__ __forceinline__ float wave_sum64(float v){
    #pragma unroll
    for (int off = 32; off > 0; off >>= 1) v += __shfl_xor(v, off, 64);
    return v;
}
__device__ __forceinline__ float siluf(float x){ return x / (1.0f + __expf(-x)); }
__device__ __forceinline__ float geluf(float x){ return 0.5f*x*(1.0f + erff(x*0.7071067811865475f)); }

__device__ __forceinline__ unsigned short f2bf(float f){   // RNE float->bf16 bits
    union { float f; unsigned u; } x; x.f = f;
    unsigned u = x.u + 0x7FFFu + ((x.u >> 16) & 1u);
    return (unsigned short)(u >> 16);
}
__device__ __forceinline__ unsigned pack2(float a, float b){
    return (unsigned)f2bf(a) | ((unsigned)f2bf(b) << 16);
}

// ---------------- 1. LayerNorm over C=96, wave per row ----------------
__global__ __launch_bounds__(256) void k_ln(const float* __restrict__ x,
                                            const float* __restrict__ w,
                                            const float* __restrict__ bb,
                                            float* __restrict__ nx){
    int row = blockIdx.x*4 + (threadIdx.x >> 6);
    int l = threadIdx.x & 63;
    const float* xr = x + (size_t)row*CC;
    float a = xr[l];
    float b = (l < 32) ? xr[64+l] : 0.0f;
    float s = wave_sum64(a + b);
    float m = s * (1.0f/96.0f);
    float d1 = a - m;
    float d2 = b - m;
    float sq = d1*d1 + ((l < 32) ? d2*d2 : 0.0f);
    float var = wave_sum64(sq) * (1.0f/96.0f);
    float rstd = rsqrtf(var + EPSF);
    float* o = nx + (size_t)row*CC;
    o[l] = d1*rstd*w[l] + bb[l];
    if (l < 32) o[64+l] = d2*rstd*w[64+l] + bb[64+l];
}

// ---------------- 2. h = silu(nx @ Wh + bh) via bf16 MFMA; split v/gate ----------------
__global__ __launch_bounds__(256) void k_hgemm(const float* __restrict__ nx,
                                               const float* __restrict__ Wh,
                                               const float* __restrict__ bh,
                                               float* __restrict__ vbuf,
                                               float* __restrict__ gate){
    __shared__ unsigned short whbf[192*100];   // [col][k] bf16, stride 100
    int tid  = threadIdx.x;
    int lane = tid & 63;
    int wid  = tid >> 6;
    int lo   = lane & 15;
    int g    = lane >> 4;
    int row0 = blockIdx.x*64 + wid*16;

    // stage Wh (96x192 fp32, row-major [k][col]) -> whbf[col][k]
    #pragma unroll
    for (int it = 0; it < 72; it++){
        int idx = tid + it*256;          // 0..18431
        int k = idx / 192, col = idx - k*192;
        whbf[col*100 + k] = f2bf(Wh[idx]);
    }

    // A-fragments: lane holds nx[row0+lo][kc*32 + g*8 .. +7]
    sh8 a[3];
    {
        const float* ar = nx + (size_t)(row0 + lo)*CC;
        #pragma unroll
        for (int kc = 0; kc < 3; kc++){
            f32x4 x0 = *(const f32x4*)(ar + kc*32 + g*8);
            f32x4 x1 = *(const f32x4*)(ar + kc*32 + g*8 + 4);
            union { unsigned u[4]; sh8 v; } pk;
            pk.u[0] = pack2(x0[0], x0[1]); pk.u[1] = pack2(x0[2], x0[3]);
            pk.u[2] = pack2(x1[0], x1[1]); pk.u[3] = pack2(x1[2], x1[3]);
            a[kc] = pk.v;
        }
    }
    __syncthreads();

    f32x4 acc[12];
    #pragma unroll
    for (int ct = 0; ct < 12; ct++) acc[ct] = (f32x4){0.f,0.f,0.f,0.f};
    #pragma unroll
    for (int ct = 0; ct < 12; ct++){
        #pragma unroll
        for (int kc = 0; kc < 3; kc++){
            sh8 bw = *(const sh8*)&whbf[(ct*16 + lo)*100 + kc*32 + g*8];
            acc[ct] = __builtin_amdgcn_mfma_f32_16x16x32_bf16(a[kc], bw, acc[ct], 0, 0, 0);
        }
    }

    // epilogue: silu(+bias), split v/gate. row = row0+g*4+j, col = ct*16+lo
    #pragma unroll
    for (int ct = 0; ct < 12; ct++){
        int col = ct*16 + lo;
        float bcol = bh[col];
        #pragma unroll
        for (int j = 0; j < 4; j++){
            size_t row = row0 + g*4 + j;
            float hv = siluf(acc[ct][j] + bcol);
            if (col < 96) vbuf[row*CC + col] = hv;
            else          gate[row*CC + col - 96] = hv;
        }
    }
}

// ---------------- 3. conv (patch GEMM, K-split) ----------------
__global__ __launch_bounds__(256) void k_conv(const float* __restrict__ nx,
                                              const float* __restrict__ wconv,
                                              float* __restrict__ part,
                                              int posLog, int pdimLog, int pszLog, int kTotal){
    __shared__ float pt[64*96];
    __shared__ float wt[96*100];
    int posPerImg = 1 << posLog;
    int pdim = 1 << pdimLog;
    int psz  = 1 << pszLog;
    int ksLog = 2*pszLog;
    int rowblocks = (NB << posLog) >> 6;
    int rb = blockIdx.x % rowblocks;
    int split = blockIdx.x / rowblocks;
    int tid = threadIdx.x;
    int to = tid & 15, ty = tid >> 4;
    float acc[4][6];
    #pragma unroll
    for (int i = 0; i < 4; i++)
        #pragma unroll
        for (int j = 0; j < 6; j++) acc[i][j] = 0.0f;

    for (int half = 0; half < 2; half++){
        int kb = split*192 + half*96;
        __syncthreads();
        for (int idx = tid; idx < 96*96; idx += 256){
            int o = idx / 96, kk = idx % 96;
            wt[o*100 + kk] = wconv[(size_t)o*kTotal + kb + kk];
        }
        for (int idx = tid; idx < 64*96; idx += 256){
            int r = idx / 96, kk = idx % 96;
            int R = rb*64 + r;
            int b = R >> posLog, p = R & (posPerImg-1);
            int k = kb + kk;
            int c = k >> ksLog, s = k & ((psz*psz)-1);
            int pi = p >> pdimLog, pj = p & (pdim-1);
            int px = (pi << pszLog) + (s >> pszLog);
            int py = (pj << pszLog) + (s & (psz-1));
            pt[r*96 + kk] = nx[((size_t)b*NTOK + px*IW + py)*CC + c];
        }
        __syncthreads();
        #pragma unroll 4
        for (int k4 = 0; k4 < 24; k4++){
            float4 xa[4], wb[6];
            #pragma unroll
            for (int i = 0; i < 4; i++)
                xa[i] = *(const float4*)&pt[(ty*4+i)*96 + k4*4];
            #pragma unroll
            for (int j = 0; j < 6; j++)
                wb[j] = *(const float4*)&wt[(to + j*16)*100 + k4*4];
            #pragma unroll
            for (int i = 0; i < 4; i++)
                #pragma unroll
                for (int j = 0; j < 6; j++){
                    acc[i][j] += xa[i].x*wb[j].x + xa[i].y*wb[j].y
                               + xa[i].z*wb[j].z + xa[i].w*wb[j].w;
                }
        }
    }
    int rowsTotal = NB << posLog;
    #pragma unroll
    for (int i = 0; i < 4; i++){
        int R = rb*64 + ty*4 + i;
        #pragma unroll
        for (int j = 0; j < 6; j++){
            int o = to + j*16;
            part[((size_t)split*rowsTotal + R)*96 + o] = acc[i][j];
        }
    }
}

// ---------------- 4. reduce K-splits + bias + LN + gelu + Z/q/k ----------------
__global__ __launch_bounds__(64) void k_reduce(const float* __restrict__ part,
                                               int nsplit, int rows,
                                               const float* __restrict__ cbias,
                                               const float* __restrict__ lw,
                                               const float* __restrict__ lb,
                                               const float* __restrict__ wqk,
                                               const float* __restrict__ bqk,
                                               const float* __restrict__ g,
                                               const float* __restrict__ be,
                                               float* __restrict__ qout,
                                               float* __restrict__ kout){
    __shared__ float xsh[96];
    int row = blockIdx.x;
    int l = threadIdx.x;
    float y1 = 0.0f, y2 = 0.0f;
    for (int s = 0; s < nsplit; s++){
        const float* pr = part + ((size_t)s*rows + row)*96;
        y1 += pr[l];
        if (l < 32) y2 += pr[64+l];
    }
    y1 += cbias[l];
    if (l < 32) y2 += cbias[64+l];
    float s = wave_sum64(y1 + ((l < 32) ? y2 : 0.0f));
    float m = s * (1.0f/96.0f);
    float d1 = y1 - m, d2 = y2 - m;
    float var = wave_sum64(d1*d1 + ((l < 32) ? d2*d2 : 0.0f)) * (1.0f/96.0f);
    float rstd = rsqrtf(var + EPSF);
    xsh[l] = geluf(d1*rstd*lw[l] + lb[l]);
    if (l < 32) xsh[64+l] = geluf(d2*rstd*lw[64+l] + lb[64+l]);
    __syncthreads();
    if (l < 48){
        float z = bqk[l];
        #pragma unroll 4
        for (int c = 0; c < 96; c++) z += xsh[c]*wqk[c*48 + l];
        z = siluf(z);
        qout[(size_t)row*48 + l] = z*g[l]    + be[l];
        kout[(size_t)row*48 + l] = z*g[48+l] + be[48+l];
    }
}

// ---------------- 5. attention via bf16 MFMA ----------------
__global__ __launch_bounds__(256) void k_attn(const float* __restrict__ vbuf,
                                              const float* __restrict__ q1,
                                              const float* __restrict__ k1,
                                              const float* __restrict__ q2,
                                              const float* __restrict__ k2,
                                              float* __restrict__ V1,
                                              float* __restrict__ V2){
    __shared__ unsigned short qbf[32*72];   // q[m][d] bf16, d padded to 64 (stride 72)
    __shared__ unsigned short ktbf[48*40];  // k^T[d][m] bf16 (stride 40)
    __shared__ float Pl[4][16*36];          // per-wave P tile [16n][32m] (stride 36)

    int bx   = blockIdx.x;
    int kind = bx >> 10;                 // 0: branch1 (M=256), 1: branch2 (M=1024)
    int blk  = bx & 1023;
    int tid  = threadIdx.x;
    int wid  = tid >> 6;
    int lane = tid & 63;
    int lo   = lane & 15;
    int g    = lane >> 4;
    int row0 = blk*64 + wid*16;          // wave's first global row (0..65535)
    int b    = row0 >> 14;               // batch

    const float* qsrc = kind ? q2 + (size_t)b*1024*48 : q1 + (size_t)b*256*48;
    const float* ksrc = kind ? k2 + (size_t)b*1024*48 : k1 + (size_t)b*256*48;
    int   M     = kind ? 1024 : 256;
    int   voff  = kind ? 48 : 0;
    float* vout = kind ? V2 : V1;

    // zero the q_bf pad region d in [48,64) once (never re-dirtied)
    {
        int m = tid >> 3, j = tid & 7;
        *(unsigned*)&qbf[m*72 + 48 + j*2] = 0u;
    }

    // v A-fragments (per-wave resident): lane holds v[row0+lo][d], d = kc*32 + g*8 .. +7
    sh8 va[2];
    {
        const float* vrow = vbuf + (size_t)(row0 + lo)*CC + voff;
        union { unsigned u[4]; sh8 v; } pk;
        f32x4 a0 = *(const f32x4*)(vrow + g*8);
        f32x4 a1 = *(const f32x4*)(vrow + g*8 + 4);
        pk.u[0] = pack2(a0[0], a0[1]); pk.u[1] = pack2(a0[2], a0[3]);
        pk.u[2] = pack2(a1[0], a1[1]); pk.u[3] = pack2(a1[2], a1[3]);
        va[0] = pk.v;
        if (g < 2){
            f32x4 b0 = *(const f32x4*)(vrow + 32 + g*8);
            f32x4 b1 = *(const f32x4*)(vrow + 32 + g*8 + 4);
            pk.u[0] = pack2(b0[0], b0[1]); pk.u[1] = pack2(b0[2], b0[3]);
            pk.u[2] = pack2(b1[0], b1[1]); pk.u[3] = pack2(b1[2], b1[3]);
        } else {
            pk.u[0] = 0u; pk.u[1] = 0u; pk.u[2] = 0u; pk.u[3] = 0u;
        }
        va[1] = pk.v;
    }

    // per-thread staging index split (constant across chunks)
    int qo[6], ko[6];
    #pragma unroll
    for (int it = 0; it < 6; it++){
        int idx = tid + it*256;          // 0..1535 over [32m][48d]
        int m = idx / 48, d = idx - m*48;
        qo[it]  = m*72 + d;              // q_bf[m][d]
        ko[it]  = d*40 + m;              // kT[d][m]
    }

    f32x4 acc[3];
    acc[0] = (f32x4){0.f,0.f,0.f,0.f};
    acc[1] = (f32x4){0.f,0.f,0.f,0.f};
    acc[2] = (f32x4){0.f,0.f,0.f,0.f};

    int nchunk = M >> 5;
    float* Pw = Pl[wid];

    for (int ch = 0; ch < nchunk; ch++){
        int mb = ch*32;
        __syncthreads();                 // protect LDS reuse (WAR) + join staging
        #pragma unroll
        for (int it = 0; it < 6; it++){
            int idx = tid + it*256;
            qbf[qo[it]]  = f2bf(qsrc[(size_t)mb*48 + idx]);
            ktbf[ko[it]] = f2bf(ksrc[(size_t)mb*48 + idx]);
        }
        __syncthreads();

        // ---- GEMM1 + relu^2 -> P ----
        #pragma unroll
        for (int mt = 0; mt < 2; mt++){
            f32x4 c = (f32x4){0.f,0.f,0.f,0.f};
            #pragma unroll
            for (int kc = 0; kc < 2; kc++){
                sh8 bq = *(const sh8*)&qbf[(mt*16 + lo)*72 + kc*32 + g*8];
                c = __builtin_amdgcn_mfma_f32_16x16x32_bf16(va[kc], bq, c, 0, 0, 0);
            }
            #pragma unroll
            for (int j = 0; j < 4; j++){
                float s = c[j] * INV_N;
                s = fmaxf(s, 0.f);
                Pw[(g*4 + j)*36 + mt*16 + lo] = s*s;
            }
        }

        // ---- GEMM2: acc += P . k ----
        sh8 pa;
        {
            f32x4 p0 = *(const f32x4*)&Pw[lo*36 + g*8];
            f32x4 p1 = *(const f32x4*)&Pw[lo*36 + g*8 + 4];
            union { unsigned u[4]; sh8 v; } pk;
            pk.u[0] = pack2(p0[0], p0[1]); pk.u[1] = pack2(p0[2], p0[3]);
            pk.u[2] = pack2(p1[0], p1[1]); pk.u[3] = pack2(p1[2], p1[3]);
            pa = pk.v;
        }
        #pragma unroll
        for (int dt = 0; dt < 3; dt++){
            sh8 bk = *(const sh8*)&ktbf[(dt*16 + lo)*40 + g*8];
            acc[dt] = __builtin_amdgcn_mfma_f32_16x16x32_bf16(pa, bk, acc[dt], 0, 0, 0);
        }
    }

    // ---- write O: row = row0 + g*4 + j, col = dt*16 + lo ----
    #pragma unroll
    for (int dt = 0; dt < 3; dt++)
        #pragma unroll
        for (int j = 0; j < 4; j++)
            vout[(size_t)(row0 + g*4 + j)*48 + dt*16 + lo] = acc[dt][j];
}

// ---------------- 6. final via bf16 MFMA: out = (xc*gate)@proj + projb + xc ----------------
// Block = 64 rows (4 waves x 16). proj staged once as bf16 [96 col][100 k].
// A = value = xc*gate (xc from V1|V2; 8-chunks never straddle col 48). 18 MFMA.
__global__ __launch_bounds__(256) void k_final(const float* __restrict__ V1,
                                               const float* __restrict__ V2,
                                               const float* __restrict__ gate,
                                               const float* __restrict__ projw,
                                               const float* __restrict__ projb,
                                               float* __restrict__ out){
    __shared__ unsigned short pjbf[96*100];    // [col][k] bf16, stride 100
    int tid  = threadIdx.x;
    int lane = tid & 63;
    int wid  = tid >> 6;
    int lo   = lane & 15;
    int g    = lane >> 4;
    int row0 = blockIdx.x*64 + wid*16;

    // stage proj_w (96x96 fp32, row-major [k][col]) -> pjbf[col][k]
    #pragma unroll
    for (int it = 0; it < 36; it++){
        int idx = tid + it*256;          // 0..9215
        int k = idx / 96, col = idx - k*96;
        pjbf[col*100 + k] = f2bf(projw[idx]);
    }

    // A-fragments: lane holds value[row0+lo][kc*32+g*8 .. +7], value = xc*gate
    sh8 a[3];
    {
        size_t row = row0 + lo;
        const float* gr = gate + row*CC;
        #pragma unroll
        for (int kc = 0; kc < 3; kc++){
            int d0 = kc*32 + g*8;
            const float* xsrc = (d0 < 48) ? (V1 + row*48 + d0) : (V2 + row*48 + d0 - 48);
            f32x4 x0 = *(const f32x4*)xsrc;
            f32x4 x1 = *(const f32x4*)(xsrc + 4);
            f32x4 g0 = *(const f32x4*)(gr + d0);
            f32x4 g1 = *(const f32x4*)(gr + d0 + 4);
            union { unsigned u[4]; sh8 v; } pk;
            pk.u[0] = pack2(x0[0]*g0[0], x0[1]*g0[1]);
            pk.u[1] = pack2(x0[2]*g0[2], x0[3]*g0[3]);
            pk.u[2] = pack2(x1[0]*g1[0], x1[1]*g1[1]);
            pk.u[3] = pack2(x1[2]*g1[2], x1[3]*g1[3]);
            a[kc] = pk.v;
        }
    }
    __syncthreads();

    f32x4 acc[6];
    #pragma unroll
    for (int ct = 0; ct < 6; ct++) acc[ct] = (f32x4){0.f,0.f,0.f,0.f};
    #pragma unroll
    for (int ct = 0; ct < 6; ct++){
        #pragma unroll
        for (int kc = 0; kc < 3; kc++){
            sh8 bw = *(const sh8*)&pjbf[(ct*16 + lo)*100 + kc*32 + g*8];
            acc[ct] = __builtin_amdgcn_mfma_f32_16x16x32_bf16(a[kc], bw, acc[ct], 0, 0, 0);
        }
    }

    // epilogue: out[row][col] = acc + projb[col] + xc[row][col]
    // row = row0 + g*4 + j, col = ct*16 + lo (col-buffer uniform per ct)
    #pragma unroll
    for (int ct = 0; ct < 6; ct++){
        int col = ct*16 + lo;
        float bcol = projb[col];
        const float* xsrc = (ct < 3) ? (V1 + col) : (V2 + col - 48);
        #pragma unroll
        for (int j = 0; j < 4; j++){
            size_t row = row0 + g*4 + j;
            float xc = xsrc[row*48];
            out[row*CC + col] = acc[ct][j] + bcol + xc;
        }
    }
}

extern "C" void kernel_launch(void* const* d_in, const int* in_sizes, int n_in,
                              void* d_out, int out_size, void* d_ws, size_t ws_size,
                              hipStream_t stream){
    const float* x      = (const float*)d_in[0];
    const float* norm_w = (const float*)d_in[3];
    const float* norm_b = (const float*)d_in[4];
    const float* Wh     = (const float*)d_in[5];
    const float* bh     = (const float*)d_in[6];
    const float* Wqk    = (const float*)d_in[7];
    const float* bqk    = (const float*)d_in[8];
    const float* g1     = (const float*)d_in[9];
    const float* be1    = (const float*)d_in[10];
    const float* g2     = (const float*)d_in[11];
    const float* be2    = (const float*)d_in[12];
    const float* sr1_w  = (const float*)d_in[13];
    const float* sr1_b  = (const float*)d_in[14];
    const float* sr2_w  = (const float*)d_in[15];
    const float* sr2_b  = (const float*)d_in[16];
    const float* n1_w   = (const float*)d_in[17];
    const float* n1_b   = (const float*)d_in[18];
    const float* n2_w   = (const float*)d_in[19];
    const float* n2_b   = (const float*)d_in[20];
    const float* proj_w = (const float*)d_in[21];
    const float* proj_b = (const float*)d_in[22];
    float* out = (float*)d_out;

    float* ws = (float*)d_ws;
    size_t off = 0;
    float* nx   = ws + off; off += (size_t)NB*NTOK*CC;
    float* vbuf = ws + off; off += (size_t)NB*NTOK*CC;
    float* gate = ws + off; off += (size_t)NB*NTOK*CC;
    float* q1   = ws + off; off += (size_t)NB*256*48;
    float* k1   = ws + off; off += (size_t)NB*256*48;
    float* q2   = ws + off; off += (size_t)NB*1024*48;
    float* k2   = ws + off; off += (size_t)NB*1024*48;
    float* part1= ws + off; off += (size_t)32*NB*256*96;
    float* part2= ws + off; off += (size_t)8*NB*1024*96;
    float* V1   = ws + off; off += (size_t)NB*NTOK*48;
    float* V2   = ws + off; off += (size_t)NB*NTOK*48;
    if (ws_size < off*sizeof(float)) return;

    k_ln   <<<16384, 256, 0, stream>>>(x, norm_w, norm_b, nx);
    k_hgemm<<<1024, 256, 0, stream>>>(nx, Wh, bh, vbuf, gate);
    k_conv <<<512, 256, 0, stream>>>(nx, sr1_w, part1, 8, 4, 3, 6144);
    k_conv <<<512, 256, 0, stream>>>(nx, sr2_w, part2, 10, 5, 2, 1536);
    k_reduce<<<1024, 64, 0, stream>>>(part1, 32, 1024, sr1_b, n1_w, n1_b, Wqk, bqk, g1, be1, q1, k1);
    k_reduce<<<4096, 64, 0, stream>>>(part2, 8, 4096, sr2_b, n2_w, n2_b, Wqk, bqk, g2, be2, q2, k2);
    k_attn <<<2048, 256, 0, stream>>>(vbuf, q1, k1, q2, k2, V1, V2);
    k_final<<<1024, 256, 0, stream>>>(V1, V2, gate, proj_w, proj_b, out);
}